// Round 2
// baseline (576.040 us; speedup 1.0000x reference)
//
#include <hip/hip_runtime.h>
#include <hip/hip_cooperative_groups.h>
#include <math.h>

namespace cg = cooperative_groups;

#define N_NODES 50000
#define N_EDGES 800000
#define C2MAX 512      // cap on in-degree of node N-1
#define K1MAX 512      // cap on |S1 ∪ {N-1}|  (layer-1 destination nodes)
#define E1MAX 8192     // cap on total layer-1 edges
#define N2MAX 2048     // cap on nodes needing xw1
#define DEGMAX 1024    // per-node in-degree cap (layer 1)

#define GRID_BLKS 512  // 2 blocks/CU on 256 CUs — guaranteed co-resident

__global__ void gat_fused(const float* __restrict__ x,
                          const int* __restrict__ eidx,
                          const float* __restrict__ W1, const float* __restrict__ aS1,
                          const float* __restrict__ aD1, const float* __restrict__ b1,
                          const float* __restrict__ W2, const float* __restrict__ aS2,
                          const float* __restrict__ aD2, const float* __restrict__ b2,
                          float* __restrict__ out, char* __restrict__ ws) {
    cg::grid_group grid = cg::this_grid();
    const int t = threadIdx.x;
    const int tid = blockIdx.x * blockDim.x + t;
    const int nthreads = gridDim.x * blockDim.x;

    const int* esrc = eidx;
    const int* edst = eidx + N_EDGES;

    // ---- workspace carve (constant offsets) ----
    int* cnt    = (int*)ws;                  // [0]=c2 [1]=K1 [2]=c1 [3]=n2
    int* slot1  = (int*)(ws + 256);
    int* slot2  = slot1 + N_NODES;
    int* e2src  = slot2 + N_NODES;
    int* l1k    = e2src + C2MAX;
    int* l1src  = l1k + E1MAX;
    int* nodes1 = l1src + E1MAX;
    int* nodes2 = nodes1 + K1MAX;
    float* xw1  = (float*)(nodes2 + N2MAX);
    float* as1  = xw1 + (size_t)N2MAX * 256;
    float* ad1  = as1 + N2MAX * 8;
    float* h1g  = ad1 + N2MAX * 8;
    float* xw2  = h1g + (size_t)K1MAX * 256;
    float* as2  = xw2 + (size_t)K1MAX * 256;
    float* ad2  = as2 + K1MAX * 8;

    __shared__ float xs[256];
    __shared__ float redS[256], redD[256];
    __shared__ int   s_elist[DEGMAX];
    __shared__ int   s_ecnt;
    __shared__ int   s_eslot[C2MAX];

    // ---- Phase 0: init slots + counters (ws is poisoned 0xAA each call) ----
    for (int u = tid; u < N_NODES; u += nthreads) { slot1[u] = -1; slot2[u] = -1; }
    if (tid < 8) cnt[tid] = 0;
    grid.sync();

    // ---- Phase A: edges with dst == N-1; mark sources (and N-1) ----
    if (tid == 0) slot1[N_NODES - 1] = -2;
    {
        const int4* edst4 = (const int4*)edst;
        for (int i = tid; i < N_EDGES / 4; i += nthreads) {
            int4 d = edst4[i];
            #pragma unroll
            for (int j = 0; j < 4; ++j) {
                int dj = (j == 0) ? d.x : (j == 1) ? d.y : (j == 2) ? d.z : d.w;
                if (dj == N_NODES - 1) {
                    int s = esrc[4 * i + j];
                    int p = atomicAdd(&cnt[0], 1);
                    if (p < C2MAX) e2src[p] = s;
                    slot1[s] = -2;   // benign race: all writers store -2
                }
            }
        }
    }
    grid.sync();

    // ---- Phase B: compact layer-1 destination nodes ----
    for (int u = tid; u < N_NODES; u += nthreads) {
        if (slot1[u] == -2) {
            int k = atomicAdd(&cnt[1], 1);
            if (k < K1MAX) { slot1[u] = k; nodes1[k] = u; }
            else slot1[u] = -1;
        }
    }
    grid.sync();

    // ---- Phase C: edges into layer-1 dsts; mark xw1-needed nodes ----
    {
        int K1 = min(cnt[1], K1MAX);
        for (int i = tid; i < K1; i += nthreads) slot2[nodes1[i]] = -2;
        const int4* edst4 = (const int4*)edst;
        for (int i = tid; i < N_EDGES / 4; i += nthreads) {
            int4 d = edst4[i];
            #pragma unroll
            for (int j = 0; j < 4; ++j) {
                int dj = (j == 0) ? d.x : (j == 1) ? d.y : (j == 2) ? d.z : d.w;
                int k = slot1[dj];
                if (k >= 0) {
                    int s = esrc[4 * i + j];
                    int p = atomicAdd(&cnt[2], 1);
                    if (p < E1MAX) { l1k[p] = k; l1src[p] = s; slot2[s] = -2; }
                }
            }
        }
    }
    grid.sync();

    // ---- Phase D: compact xw1 nodes ----
    for (int u = tid; u < N_NODES; u += nthreads) {
        if (slot2[u] == -2) {
            int m = atomicAdd(&cnt[3], 1);
            if (m < N2MAX) { slot2[u] = m; nodes2[m] = u; }
            else slot2[u] = -1;
        }
    }
    grid.sync();

    // ---- Phase E: xw1 = x[u] @ W1^T, plus a_src1/a_dst1 ----
    {
        int n2 = min(cnt[3], N2MAX);
        for (int b = blockIdx.x; b < n2; b += gridDim.x) {
            int u = nodes2[b];
            xs[t] = x[(size_t)u * 256 + t];
            __syncthreads();
            const float4* wrow = (const float4*)(W1 + (size_t)t * 256);
            float acc = 0.f;
            #pragma unroll 8
            for (int c = 0; c < 64; ++c) {
                float4 w = wrow[c];
                float4 xv = *(const float4*)&xs[4 * c];
                acc = fmaf(xv.x, w.x, acc); acc = fmaf(xv.y, w.y, acc);
                acc = fmaf(xv.z, w.z, acc); acc = fmaf(xv.w, w.w, acc);
            }
            xw1[(size_t)b * 256 + t] = acc;
            redS[t] = acc * aS1[t];
            redD[t] = acc * aD1[t];
            __syncthreads();
            if ((t & 31) == 0) {
                int h = t >> 5;
                float s = 0.f, d = 0.f;
                for (int i = 0; i < 32; ++i) { s += redS[t + i]; d += redD[t + i]; }
                as1[b * 8 + h] = s;
                ad1[b * 8 + h] = d;
            }
            __syncthreads();
        }
    }
    grid.sync();

    // ---- Phase F: layer-1 attention + aggregate + bias + exact GELU ----
    {
        int K1 = min(cnt[1], K1MAX);
        int c1 = min(cnt[2], E1MAX);
        int h = t >> 5;
        for (int k = blockIdx.x; k < K1; k += gridDim.x) {
            if (t == 0) s_ecnt = 0;
            __syncthreads();
            for (int j = t; j < c1; j += 256) {
                if (l1k[j] == k) {
                    int p = atomicAdd(&s_ecnt, 1);
                    if (p < DEGMAX) s_elist[p] = l1src[j];
                }
            }
            __syncthreads();
            int ne = min(s_ecnt, DEGMAX);
            int u = nodes1[k];
            float adst = ad1[slot2[u] * 8 + h];
            float m = -INFINITY;
            for (int j = 0; j < ne; ++j) {
                int s2 = slot2[s_elist[j]];
                float e = as1[s2 * 8 + h] + adst;
                e = (e >= 0.f) ? e : 0.2f * e;
                m = fmaxf(m, e);
            }
            float denom = 0.f, acc = 0.f;
            for (int j = 0; j < ne; ++j) {
                int s2 = slot2[s_elist[j]];
                float e = as1[s2 * 8 + h] + adst;
                e = (e >= 0.f) ? e : 0.2f * e;
                float p = expf(e - m);
                denom += p;
                acc = fmaf(p, xw1[(size_t)s2 * 256 + t], acc);
            }
            float o = (ne > 0) ? acc / (denom + 1e-16f) : 0.f;
            o += b1[t];
            // exact GELU: x * 0.5 * (1 + erf(x/sqrt(2)))
            h1g[(size_t)k * 256 + t] = 0.5f * o * (1.f + erff(o * 0.70710678118654752440f));
            __syncthreads();
        }
    }
    grid.sync();

    // ---- Phase G: xw2 = h1g[k] @ W2^T, plus a_src2/a_dst2 ----
    {
        int K1 = min(cnt[1], K1MAX);
        for (int b = blockIdx.x; b < K1; b += gridDim.x) {
            xs[t] = h1g[(size_t)b * 256 + t];
            __syncthreads();
            const float4* wrow = (const float4*)(W2 + (size_t)t * 256);
            float acc = 0.f;
            #pragma unroll 8
            for (int c = 0; c < 64; ++c) {
                float4 w = wrow[c];
                float4 xv = *(const float4*)&xs[4 * c];
                acc = fmaf(xv.x, w.x, acc); acc = fmaf(xv.y, w.y, acc);
                acc = fmaf(xv.z, w.z, acc); acc = fmaf(xv.w, w.w, acc);
            }
            xw2[(size_t)b * 256 + t] = acc;
            redS[t] = acc * aS2[t];
            redD[t] = acc * aD2[t];
            __syncthreads();
            if ((t & 31) == 0) {
                int h = t >> 5;
                float s = 0.f, d = 0.f;
                for (int i = 0; i < 32; ++i) { s += redS[t + i]; d += redD[t + i]; }
                as2[b * 8 + h] = s;
                ad2[b * 8 + h] = d;
            }
            __syncthreads();
        }
    }
    grid.sync();

    // ---- Phase H: layer-2 attention for node N-1 (block 0 only) ----
    if (blockIdx.x == 0) {
        int h = t >> 5;
        int c2 = min(cnt[0], C2MAX);
        int kd = slot1[N_NODES - 1];
        for (int j = t; j < c2; j += 256) s_eslot[j] = slot1[e2src[j]];
        __syncthreads();
        float adst = ad2[kd * 8 + h];
        float m = -INFINITY;
        for (int j = 0; j < c2; ++j) {
            float e = as2[s_eslot[j] * 8 + h] + adst;
            e = (e >= 0.f) ? e : 0.2f * e;
            m = fmaxf(m, e);
        }
        float denom = 0.f, acc = 0.f;
        for (int j = 0; j < c2; ++j) {
            int kk = s_eslot[j];
            float e = as2[kk * 8 + h] + adst;
            e = (e >= 0.f) ? e : 0.2f * e;
            float p = expf(e - m);
            denom += p;
            acc = fmaf(p, xw2[(size_t)kk * 256 + t], acc);
        }
        float o = (c2 > 0) ? acc / (denom + 1e-16f) : 0.f;
        out[t] = o + b2[t];
    }
}

extern "C" void kernel_launch(void* const* d_in, const int* in_sizes, int n_in,
                              void* d_out, int out_size, void* d_ws, size_t ws_size,
                              hipStream_t stream) {
    const float* x    = (const float*)d_in[0];
    const int*   eidx = (const int*)d_in[1];
    const float* W1   = (const float*)d_in[2];
    const float* aS1  = (const float*)d_in[3];
    const float* aD1  = (const float*)d_in[4];
    const float* b1   = (const float*)d_in[5];
    const float* W2   = (const float*)d_in[6];
    const float* aS2  = (const float*)d_in[7];
    const float* aD2  = (const float*)d_in[8];
    const float* b2   = (const float*)d_in[9];
    float* out = (float*)d_out;
    char*  ws  = (char*)d_ws;

    void* args[] = {
        (void*)&x, (void*)&eidx, (void*)&W1, (void*)&aS1, (void*)&aD1, (void*)&b1,
        (void*)&W2, (void*)&aS2, (void*)&aD2, (void*)&b2, (void*)&out, (void*)&ws
    };
    hipLaunchCooperativeKernel((const void*)gat_fused, dim3(GRID_BLKS), dim3(256),
                               args, 0, stream);
}

// Round 3
// 339.529 us; speedup vs baseline: 1.6966x; 1.6966x over previous
//
#include <hip/hip_runtime.h>
#include <math.h>

#define N_NODES 50000
#define N_EDGES 800000
#define TGT     (N_NODES - 1)
#define C2MAX 256      // cap on in-degree of node N-1 (E[deg]=16)
#define K1MAX 128      // cap on unique layer-1 dst nodes (sources of N-1 edges + N-1)
#define E1MAX 2048     // cap on total layer-1 edges (E ~ 17*16 = 272)
#define ELMAX 512      // per-dst gathered edge cap
#define NBLK  512      // 2 blocks/CU on 256 CUs — co-resident under cooperative launch
#define NTHR  256

__device__ __forceinline__ int findk(const int* u, int K, int v) {
    for (int i = 0; i < K; ++i) if (u[i] == v) return i;
    return -1;
}

// Lean grid barrier: single monotone counter, release-add + relaxed polls.
// target = phase_index * NBLK. All blocks guaranteed co-resident (cooperative launch).
__device__ __forceinline__ void gbar(unsigned* bar, unsigned target, bool spin) {
    __syncthreads();                    // emits s_waitcnt vmcnt(0) + s_barrier: block's stores are in L2
    if (threadIdx.x == 0) {
        __threadfence();                // release: write back XCD L2 so other XCDs see our data
        __hip_atomic_fetch_add(bar, 1u, __ATOMIC_RELEASE, __HIP_MEMORY_SCOPE_AGENT);
        if (spin) {
            while (__hip_atomic_load(bar, __ATOMIC_RELAXED, __HIP_MEMORY_SCOPE_AGENT) < target)
                __builtin_amdgcn_s_sleep(2);
            __threadfence();            // acquire: invalidate L1/L2 so we read others' data fresh
        }
    }
    __syncthreads();
}

__global__ __launch_bounds__(NTHR, 2) void gat_fused(
        const float* __restrict__ x, const int* __restrict__ eidx,
        const float* __restrict__ W1, const float* __restrict__ aS1,
        const float* __restrict__ aD1, const float* __restrict__ b1,
        const float* __restrict__ W2, const float* __restrict__ aS2,
        const float* __restrict__ aD2, const float* __restrict__ b2,
        float* __restrict__ out, char* __restrict__ ws) {
    const int t   = threadIdx.x;
    const int tid = blockIdx.x * NTHR + t;
    const int nthreads = NBLK * NTHR;

    const int* esrc = eidx;
    const int* edst = eidx + N_EDGES;

    // ---- workspace carve ----
    int*      cnt  = (int*)ws;                     // cnt[0]=c2, cnt[2]=c1, cnt[8]=barrier (memset to 0)
    unsigned* bar  = (unsigned*)&cnt[8];
    int*   e2src = cnt + 64;                       // [C2MAX]
    int*   l1k   = e2src + C2MAX;                  // [E1MAX] dst-slot per layer-1 edge
    int*   l1src = l1k + E1MAX;                    // [E1MAX] source node per layer-1 edge
    float* W1T   = (float*)(l1src + E1MAX);        // [256*256] transposed W1
    float* W2T   = W1T + 65536;                    // [256*256]
    float* xw1   = W2T + 65536;                    // [(E1MAX+K1MAX)*256] per-item xW1^T
    float* as1   = xw1 + (size_t)(E1MAX + K1MAX) * 256;   // [(E1MAX+K1MAX)*8]
    float* ad1   = as1 + (E1MAX + K1MAX) * 8;
    float* xw2   = ad1 + (E1MAX + K1MAX) * 8;      // [K1MAX*256]
    float* as2   = xw2 + K1MAX * 256;              // [K1MAX*8]
    float* ad2   = as2 + K1MAX * 8;

    __shared__ int   s_uniq[K1MAX];    // unique layer-1 dst nodes (identical in every block)
    __shared__ int   s_slotOf[C2MAX];  // layer-2 edge j -> dst slot k
    __shared__ int   s_K1, s_kd;
    __shared__ float s_xsT[4 * 256];   // 4 nodes' features, interleaved [c][i]
    __shared__ float s_redS[4 * 256], s_redD[4 * 256];
    __shared__ int   s_elist[ELMAX];
    __shared__ int   s_ne;
    __shared__ float s_h1[256];

    // ================= Phase A: transpose W1/W2; scan edges with dst==N-1 ========
    for (int i = tid; i < 65536; i += nthreads) {
        int o = i >> 8, c = i & 255;          // coalesced read, scattered write (L2-absorbed)
        W1T[c * 256 + o] = W1[i];
        W2T[c * 256 + o] = W2[i];
    }
    {
        const int4* edst4 = (const int4*)edst;
        for (int i = tid; i < N_EDGES / 4; i += nthreads) {
            int4 d = edst4[i];
            int dv[4] = {d.x, d.y, d.z, d.w};
            #pragma unroll
            for (int j = 0; j < 4; ++j) {
                if (dv[j] == TGT) {
                    int p = atomicAdd(&cnt[0], 1);
                    if (p < C2MAX) e2src[p] = esrc[4 * i + j];
                }
            }
        }
    }
    gbar(bar, 1u * NBLK, true);

    // ================= Phase C: dedup (every block, identical result); scan edges into dst set
    if (t == 0) {
        int c2 = min(cnt[0], C2MAX);
        int K1 = 0;
        for (int j = 0; j < c2; ++j) {
            int s = e2src[j];
            int k = findk(s_uniq, K1, s);
            if (k < 0) { if (K1 < K1MAX) { s_uniq[K1] = s; k = K1; K1++; } else k = 0; }
            s_slotOf[j] = k;
        }
        int kd = findk(s_uniq, K1, TGT);
        if (kd < 0) { kd = K1; s_uniq[K1++] = TGT; }
        s_K1 = K1; s_kd = kd;
    }
    __syncthreads();
    {
        int K1 = s_K1;
        const int4* edst4 = (const int4*)edst;
        for (int i = tid; i < N_EDGES / 4; i += nthreads) {
            int4 d = edst4[i];
            int dv[4] = {d.x, d.y, d.z, d.w};
            #pragma unroll
            for (int j = 0; j < 4; ++j) {
                int k = findk(s_uniq, K1, dv[j]);
                if (k >= 0) {
                    int p = atomicAdd(&cnt[2], 1);
                    if (p < E1MAX) { l1k[p] = k; l1src[p] = esrc[4 * i + j]; }
                }
            }
        }
    }
    gbar(bar, 2u * NBLK, true);

    // ================= Phase E: xw1 per work item (c1 edge entries + K1 dst nodes) =
    {
        int c1 = min(cnt[2], E1MAX);
        int nitems = c1 + s_K1;
        for (int base = blockIdx.x * 4; base < nitems; base += NBLK * 4) {
            int na = min(4, nitems - base);
            for (int i = 0; i < na; ++i) {
                int it = base + i;
                int node = (it < c1) ? l1src[it] : s_uniq[it - c1];
                s_xsT[t * 4 + i] = x[(size_t)node * 256 + t];
            }
            __syncthreads();
            float a0 = 0.f, a1 = 0.f, a2 = 0.f, a3 = 0.f;
            #pragma unroll 8
            for (int c = 0; c < 256; ++c) {
                float w = W1T[c * 256 + t];          // lane-coalesced
                float4 xv = *(const float4*)&s_xsT[c * 4];  // broadcast b128
                a0 = fmaf(xv.x, w, a0); a1 = fmaf(xv.y, w, a1);
                a2 = fmaf(xv.z, w, a2); a3 = fmaf(xv.w, w, a3);
            }
            float accs[4] = {a0, a1, a2, a3};
            for (int i = 0; i < na; ++i) {
                xw1[(size_t)(base + i) * 256 + t] = accs[i];
                s_redS[i * 256 + t] = accs[i] * aS1[t];
                s_redD[i * 256 + t] = accs[i] * aD1[t];
            }
            __syncthreads();
            if (t < 32) {                           // t = item*8 + head
                int i = t >> 3, h = t & 7;
                if (i < na) {
                    float s = 0.f, dd = 0.f;
                    for (int q = 0; q < 32; ++q) {
                        s  += s_redS[i * 256 + h * 32 + q];
                        dd += s_redD[i * 256 + h * 32 + q];
                    }
                    as1[(base + i) * 8 + h] = s;
                    ad1[(base + i) * 8 + h] = dd;
                }
            }
            __syncthreads();
        }
    }
    gbar(bar, 3u * NBLK, true);

    // ================= Phase FG: per-dst attn softmax + aggregate + GELU + xw2 ====
    {
        int K1 = s_K1;
        int c1 = min(cnt[2], E1MAX);
        if (blockIdx.x < K1) {
            int k = blockIdx.x;
            if (t == 0) s_ne = 0;
            __syncthreads();
            for (int j = t; j < c1; j += NTHR)
                if (l1k[j] == k) { int p = atomicAdd(&s_ne, 1); if (p < ELMAX) s_elist[p] = j; }
            __syncthreads();
            int ne = min(s_ne, ELMAX);
            int h = t >> 5;
            float adst = ad1[(c1 + k) * 8 + h];
            float m = -INFINITY;
            for (int j = 0; j < ne; ++j) {
                float e = as1[s_elist[j] * 8 + h] + adst;
                e = (e >= 0.f) ? e : 0.2f * e;
                m = fmaxf(m, e);
            }
            float denom = 0.f, acc = 0.f;
            for (int j = 0; j < ne; ++j) {
                int jj = s_elist[j];
                float e = as1[jj * 8 + h] + adst;
                e = (e >= 0.f) ? e : 0.2f * e;
                float p = expf(e - m);
                denom += p;
                acc = fmaf(p, xw1[(size_t)jj * 256 + t], acc);
            }
            float o = (ne > 0) ? acc / (denom + 1e-16f) : 0.f;
            o += b1[t];
            s_h1[t] = 0.5f * o * (1.f + erff(o * 0.70710678118654752440f));  // exact GELU
            __syncthreads();
            float a2 = 0.f;
            #pragma unroll 8
            for (int c = 0; c < 256; ++c)
                a2 = fmaf(s_h1[c], W2T[c * 256 + t], a2);
            xw2[k * 256 + t] = a2;
            s_redS[t] = a2 * aS2[t];
            s_redD[t] = a2 * aD2[t];
            __syncthreads();
            if (t < 8) {
                float s = 0.f, dd = 0.f;
                for (int q = 0; q < 32; ++q) { s += s_redS[t * 32 + q]; dd += s_redD[t * 32 + q]; }
                as2[k * 8 + t] = s;
                ad2[k * 8 + t] = dd;
            }
        }
    }
    gbar(bar, 4u * NBLK, blockIdx.x == 0);
    if (blockIdx.x != 0) return;

    // ================= Phase H: layer-2 attention for node N-1 (block 0) ==========
    {
        int c2 = min(cnt[0], C2MAX);
        int h = t >> 5;
        float adst = ad2[s_kd * 8 + h];
        float m = -INFINITY;
        for (int j = 0; j < c2; ++j) {
            float e = as2[s_slotOf[j] * 8 + h] + adst;
            e = (e >= 0.f) ? e : 0.2f * e;
            m = fmaxf(m, e);
        }
        float denom = 0.f, acc = 0.f;
        for (int j = 0; j < c2; ++j) {
            int kk = s_slotOf[j];
            float e = as2[kk * 8 + h] + adst;
            e = (e >= 0.f) ? e : 0.2f * e;
            float p = expf(e - m);
            denom += p;
            acc = fmaf(p, xw2[kk * 256 + t], acc);
        }
        float o = (c2 > 0) ? acc / (denom + 1e-16f) : 0.f;
        out[t] = o + b2[t];
    }
}

extern "C" void kernel_launch(void* const* d_in, const int* in_sizes, int n_in,
                              void* d_out, int out_size, void* d_ws, size_t ws_size,
                              hipStream_t stream) {
    const float* x    = (const float*)d_in[0];
    const int*   eidx = (const int*)d_in[1];
    const float* W1   = (const float*)d_in[2];
    const float* aS1  = (const float*)d_in[3];
    const float* aD1  = (const float*)d_in[4];
    const float* b1   = (const float*)d_in[5];
    const float* W2   = (const float*)d_in[6];
    const float* aS2  = (const float*)d_in[7];
    const float* aD2  = (const float*)d_in[8];
    const float* b2   = (const float*)d_in[9];
    float* out = (float*)d_out;
    char*  ws  = (char*)d_ws;

    hipMemsetAsync(ws, 0, 64, stream);   // zero cnt[0..15] incl. barrier counter

    void* args[] = {
        (void*)&x, (void*)&eidx, (void*)&W1, (void*)&aS1, (void*)&aD1, (void*)&b1,
        (void*)&W2, (void*)&aS2, (void*)&aD2, (void*)&b2, (void*)&out, (void*)&ws
    };
    hipLaunchCooperativeKernel((const void*)gat_fused, dim3(NBLK), dim3(NTHR),
                               args, 0, stream);
}

// Round 4
// 166.939 us; speedup vs baseline: 3.4506x; 2.0338x over previous
//
#include <hip/hip_runtime.h>
#include <math.h>

#define N_NODES 50000
#define N_EDGES 800000
#define TGT     (N_NODES - 1)
#define C2MAX   256      // cap on in-degree of node N-1 (E[deg]=16, P(>256)~0)
#define KCAP    258      // max unique layer-1 dst nodes (<= C2MAX+1)
#define ELMAX   256      // per-dst layer-1 edge cap
#define XWLDS   32       // xw1 items kept in LDS per block; beyond spills to global
#define SCANBLK 1024

// ---------------- workspace carve ----------------
struct WS {
  int* cnt;      // [16]      cnt[0] = #edges into TGT          (memset 0)
  int* cnt2;     // [272]     per-dst-slot edge counters        (memset 0)
  int* e2src;    // [C2MAX]   sources of TGT's in-edges
  int* g_uniq;   // [272]     unique layer-1 dst nodes (published by k_scan1 blk0)
  int* g_slot;   // [C2MAX]   layer-2 edge j -> dst slot
  int* g_misc;   // [16]      [0]=K1, [1]=kd
  int* l1src;    // [KCAP*ELMAX] per-dst source lists
  float* W1T;    // [65536]
  float* W2T;    // [65536]
  float* g_xw2;  // [KCAP*256]
  float* g_as2;  // [KCAP*8]
  float* g_ad2;  // [KCAP*8]
  float* g_spill;// [KCAP*(ELMAX+1)*256]  (~68 MB, rarely touched)
};
__host__ __device__ inline WS carve(char* ws) {
  WS w; int* p = (int*)ws;
  w.cnt = p;    p += 16;
  w.cnt2 = p;   p += 272;
  w.e2src = p;  p += C2MAX;
  w.g_uniq = p; p += 272;
  w.g_slot = p; p += C2MAX;
  w.g_misc = p; p += 16;
  w.l1src = p;  p += KCAP * ELMAX;
  float* f = (float*)p;
  w.W1T = f;    f += 65536;
  w.W2T = f;    f += 65536;
  w.g_xw2 = f;  f += KCAP * 256;
  w.g_as2 = f;  f += KCAP * 8;
  w.g_ad2 = f;  f += KCAP * 8;
  w.g_spill = f;
  return w;
}

// Deterministic per-block dedup of e2src[0..c2): first-occurrence ranks via
// LDS prefix-sum. Same input -> same result in every block, no coordination.
__device__ void dedup_block(const int* e2src, int c2, int* s_e, int* s_scan,
                            int* s_uniq, int* s_slot, int* s_kv) {
  int t = threadIdx.x;
  if (t < c2) s_e[t] = e2src[t];
  __syncthreads();
  int s = 0, firstIdx = t;
  if (t < c2) {
    s = s_e[t];
    for (int q = 0; q < t; ++q) if (s_e[q] == s) { firstIdx = q; break; }
  }
  s_scan[t] = (t < c2 && firstIdx == t) ? 1 : 0;
  __syncthreads();
  for (int off = 1; off < 256; off <<= 1) {       // inclusive Hillis-Steele
    int add = (t >= off) ? s_scan[t - off] : 0;
    __syncthreads();
    s_scan[t] += add;
    __syncthreads();
  }
  if (t < c2 && firstIdx == t) s_uniq[s_scan[t] - 1] = s;
  __syncthreads();
  if (t < c2) s_slot[t] = s_scan[firstIdx] - 1;
  if (t == 0) {
    int K1 = (c2 > 0) ? s_scan[255] : 0;
    int kd = -1;
    for (int i = 0; i < K1; ++i) if (s_uniq[i] == TGT) { kd = i; break; }
    if (kd < 0) { s_uniq[K1] = TGT; kd = K1; K1++; }
    s_kv[0] = K1; s_kv[1] = kd;
  }
  __syncthreads();
}

// ---- K1: transpose W1/W2; scan edges with dst == TGT ----
__global__ __launch_bounds__(256) void k_scan2(const int* __restrict__ eidx,
    const float* __restrict__ W1, const float* __restrict__ W2, char* ws) {
  WS w = carve(ws);
  int tid = blockIdx.x * 256 + threadIdx.x;
  int nthreads = gridDim.x * 256;
  for (int i = tid; i < 65536; i += nthreads) {
    int o = i >> 8, c = i & 255;
    w.W1T[c * 256 + o] = W1[i];
    w.W2T[c * 256 + o] = W2[i];
  }
  const int* esrc = eidx;
  const int4* edst4 = (const int4*)(eidx + N_EDGES);
  for (int i = tid; i < N_EDGES / 4; i += nthreads) {
    int4 d = edst4[i];
    int dv[4] = {d.x, d.y, d.z, d.w};
#pragma unroll
    for (int j = 0; j < 4; ++j)
      if (dv[j] == TGT) {
        int p = atomicAdd(&w.cnt[0], 1);
        if (p < C2MAX) w.e2src[p] = esrc[4 * i + j];
      }
  }
}

// ---- K2: per-block dedup; scan edges into dst set -> per-dst lists ----
__global__ __launch_bounds__(256) void k_scan1(const int* __restrict__ eidx, char* ws) {
  WS w = carve(ws);
  __shared__ int s_e[C2MAX], s_scan[256], s_uniq[KCAP], s_slot[C2MAX], s_kv[2];
  int c2 = min(w.cnt[0], C2MAX);
  dedup_block(w.e2src, c2, s_e, s_scan, s_uniq, s_slot, s_kv);
  int K1 = s_kv[0];
  if (blockIdx.x == 0) {
    int t = threadIdx.x;
    if (t < K1) w.g_uniq[t] = s_uniq[t];
    if (t < c2) w.g_slot[t] = s_slot[t];
    if (t == 0) { w.g_misc[0] = K1; w.g_misc[1] = s_kv[1]; }
  }
  int tid = blockIdx.x * 256 + threadIdx.x;
  int nthreads = gridDim.x * 256;
  const int* esrc = eidx;
  const int4* edst4 = (const int4*)(eidx + N_EDGES);
  for (int i = tid; i < N_EDGES / 4; i += nthreads) {
    int4 d = edst4[i];
    int dv[4] = {d.x, d.y, d.z, d.w};
#pragma unroll
    for (int j = 0; j < 4; ++j) {
      int k = -1;
      for (int q = 0; q < K1; ++q) if (s_uniq[q] == dv[j]) { k = q; break; }
      if (k >= 0) {
        int p = atomicAdd(&w.cnt2[k], 1);
        if (p < ELMAX) w.l1src[k * ELMAX + p] = esrc[4 * i + j];
      }
    }
  }
}

// ---- K3: one block per unique layer-1 dst: xw1 batch, attn, GELU, xw2 ----
__global__ __launch_bounds__(256) void k_gat(const float* __restrict__ x,
    const float* __restrict__ aS1, const float* __restrict__ aD1,
    const float* __restrict__ b1, const float* __restrict__ aS2,
    const float* __restrict__ aD2, char* ws) {
  WS w = carve(ws);
  int K1 = w.g_misc[0];
  int k = blockIdx.x;
  if (k >= K1) return;
  int t = threadIdx.x;
  __shared__ float s_xw[XWLDS * 256];                // 32 KB
  __shared__ float s_as[(ELMAX + 1) * 8];            // 8.2 KB
  __shared__ float s_ad[(ELMAX + 1) * 8];            // 8.2 KB
  __shared__ __align__(16) float s_xsT[4 * 256];     // 4 KB
  __shared__ float s_redS[4 * 256], s_redD[4 * 256]; // 8 KB
  __shared__ float s_h1[256];
  int myNode = w.g_uniq[k];
  int ne = min(w.cnt2[k], ELMAX);
  int items = ne + 1;                                // edges + the dst node itself
  float* spill = w.g_spill + (size_t)k * (ELMAX + 1) * 256;

  for (int base = 0; base < items; base += 4) {
    int na = min(4, items - base);
    int nd[4];
    for (int i = 0; i < na; ++i) {
      int it = base + i;
      nd[i] = (it < ne) ? w.l1src[k * ELMAX + it] : myNode;
    }
    for (int i = 0; i < na; ++i)
      s_xsT[t * 4 + i] = x[(size_t)nd[i] * 256 + t];
    __syncthreads();
    float a0 = 0.f, a1 = 0.f, a2 = 0.f, a3 = 0.f;
#pragma unroll 16
    for (int c = 0; c < 256; ++c) {
      float wv = w.W1T[c * 256 + t];                 // lane-coalesced, L2-resident
      float4 xv = *(const float4*)&s_xsT[c * 4];     // LDS broadcast
      a0 = fmaf(xv.x, wv, a0); a1 = fmaf(xv.y, wv, a1);
      a2 = fmaf(xv.z, wv, a2); a3 = fmaf(xv.w, wv, a3);
    }
    float accs[4] = {a0, a1, a2, a3};
    for (int i = 0; i < na; ++i) {
      int it = base + i;
      if (it < XWLDS) s_xw[it * 256 + t] = accs[i];
      else            spill[(size_t)it * 256 + t] = accs[i];
      s_redS[i * 256 + t] = accs[i] * aS1[t];
      s_redD[i * 256 + t] = accs[i] * aD1[t];
    }
    __syncthreads();
    if (t < 32) {
      int i = t >> 3, h = t & 7;
      if (i < na) {
        float s = 0.f, dd = 0.f;
        for (int q = 0; q < 32; ++q) {
          s  += s_redS[i * 256 + h * 32 + q];
          dd += s_redD[i * 256 + h * 32 + q];
        }
        s_as[(base + i) * 8 + h] = s;
        s_ad[(base + i) * 8 + h] = dd;
      }
    }
    __syncthreads();
  }

  int h = t >> 5;
  float adst = s_ad[ne * 8 + h];                     // dst node is item `ne`
  float m = -INFINITY;
  for (int j = 0; j < ne; ++j) {
    float e = s_as[j * 8 + h] + adst;
    e = (e >= 0.f) ? e : 0.2f * e;
    m = fmaxf(m, e);
  }
  float denom = 0.f, acc = 0.f;
  for (int j = 0; j < ne; ++j) {
    float e = s_as[j * 8 + h] + adst;
    e = (e >= 0.f) ? e : 0.2f * e;
    float p = expf(e - m);
    denom += p;
    float xv = (j < XWLDS) ? s_xw[j * 256 + t] : spill[(size_t)j * 256 + t];
    acc = fmaf(p, xv, acc);
  }
  float o = (ne > 0) ? acc / (denom + 1e-16f) : 0.f;
  o += b1[t];
  s_h1[t] = 0.5f * o * (1.f + erff(o * 0.70710678118654752440f));  // exact GELU
  __syncthreads();
  float a2s = 0.f;
#pragma unroll 16
  for (int c = 0; c < 256; ++c)
    a2s = fmaf(s_h1[c], w.W2T[c * 256 + t], a2s);
  w.g_xw2[k * 256 + t] = a2s;
  s_redS[t] = a2s * aS2[t];
  s_redD[t] = a2s * aD2[t];
  __syncthreads();
  if (t < 8) {
    float s = 0.f, dd = 0.f;
    for (int q = 0; q < 32; ++q) { s += s_redS[t * 32 + q]; dd += s_redD[t * 32 + q]; }
    w.g_as2[k * 8 + t] = s;
    w.g_ad2[k * 8 + t] = dd;
  }
}

// ---- K4: layer-2 attention for node TGT ----
__global__ __launch_bounds__(256) void k_final(const float* __restrict__ b2,
                                               float* __restrict__ out, char* ws) {
  WS w = carve(ws);
  int t = threadIdx.x;
  int c2 = min(w.cnt[0], C2MAX);
  int kd = w.g_misc[1];
  __shared__ int s_slot[C2MAX];
  if (t < c2) s_slot[t] = w.g_slot[t];
  __syncthreads();
  int h = t >> 5;
  float adst = w.g_ad2[kd * 8 + h];
  float m = -INFINITY;
  for (int j = 0; j < c2; ++j) {
    float e = w.g_as2[s_slot[j] * 8 + h] + adst;
    e = (e >= 0.f) ? e : 0.2f * e;
    m = fmaxf(m, e);
  }
  float denom = 0.f, acc = 0.f;
  for (int j = 0; j < c2; ++j) {
    int kk = s_slot[j];
    float e = w.g_as2[kk * 8 + h] + adst;
    e = (e >= 0.f) ? e : 0.2f * e;
    float p = expf(e - m);
    denom += p;
    acc = fmaf(p, w.g_xw2[kk * 256 + t], acc);
  }
  float o = (c2 > 0) ? acc / (denom + 1e-16f) : 0.f;
  out[t] = o + b2[t];
}

extern "C" void kernel_launch(void* const* d_in, const int* in_sizes, int n_in,
                              void* d_out, int out_size, void* d_ws, size_t ws_size,
                              hipStream_t stream) {
  const float* x    = (const float*)d_in[0];
  const int*   eidx = (const int*)d_in[1];
  const float* W1   = (const float*)d_in[2];
  const float* aS1  = (const float*)d_in[3];
  const float* aD1  = (const float*)d_in[4];
  const float* b1   = (const float*)d_in[5];
  const float* W2   = (const float*)d_in[6];
  const float* aS2  = (const float*)d_in[7];
  const float* aD2  = (const float*)d_in[8];
  const float* b2   = (const float*)d_in[9];
  float* out = (float*)d_out;
  char*  ws  = (char*)d_ws;

  hipMemsetAsync(ws, 0, (16 + 272) * sizeof(int), stream);  // cnt + cnt2 only

  k_scan2<<<SCANBLK, 256, 0, stream>>>(eidx, W1, W2, ws);
  k_scan1<<<SCANBLK, 256, 0, stream>>>(eidx, ws);
  k_gat  <<<KCAP,    256, 0, stream>>>(x, aS1, aD1, b1, aS2, aD2, ws);
  k_final<<<1,       256, 0, stream>>>(b2, out, ws);
}

// Round 5
// 142.908 us; speedup vs baseline: 4.0308x; 1.1682x over previous
//
#include <hip/hip_runtime.h>
#include <math.h>

#define N_NODES 50000
#define N_EDGES 800000
#define TGT     (N_NODES - 1)
#define C2MAX   256      // cap on in-degree of node N-1 (E[deg]=16)
#define KCAP    258      // max unique layer-1 dst nodes (<= C2MAX+1)
#define ELMAX   256      // per-dst layer-1 edge cap
#define ROWS    (ELMAX + 1)
#define PBLK    16       // y-grid of k_xw1: batches strided by PBLK
#define SCANBLK 1024

// ---------------- workspace carve ----------------
struct WS {
  int* cnt;      // [16]      cnt[0] = #edges into TGT          (memset 0)
  int* cnt2;     // [272]     per-dst-slot edge counters        (memset 0)
  int* e2src;    // [C2MAX]   sources of TGT's in-edges
  int* g_uniq;   // [272]     unique layer-1 dst nodes
  int* g_slot;   // [C2MAX]   layer-2 edge j -> dst slot
  int* g_misc;   // [16]      [0]=K1, [1]=kd
  int* l1src;    // [KCAP*ELMAX] per-dst source lists
  float* W1T;    // [65536]
  float* W2T;    // [65536]
  float* g_xw2;  // [KCAP*256]
  float* g_as2;  // [KCAP*8]
  float* g_ad2;  // [KCAP*8]
  float* g_as1;  // [KCAP*ROWS*8]
  float* g_ad1;  // [KCAP*ROWS*8]
  float* g_xw1;  // [KCAP*ROWS*256] (~68 MB)
};
__host__ __device__ inline WS carve(char* ws) {
  WS w; int* p = (int*)ws;
  w.cnt = p;    p += 16;
  w.cnt2 = p;   p += 272;
  w.e2src = p;  p += C2MAX;
  w.g_uniq = p; p += 272;
  w.g_slot = p; p += C2MAX;
  w.g_misc = p; p += 16;
  w.l1src = p;  p += KCAP * ELMAX;
  float* f = (float*)p;
  w.W1T = f;    f += 65536;
  w.W2T = f;    f += 65536;
  w.g_xw2 = f;  f += KCAP * 256;
  w.g_as2 = f;  f += KCAP * 8;
  w.g_ad2 = f;  f += KCAP * 8;
  w.g_as1 = f;  f += KCAP * ROWS * 8;
  w.g_ad1 = f;  f += KCAP * ROWS * 8;
  w.g_xw1 = f;
  return w;
}

// Deterministic per-block dedup of e2src[0..c2): first-occurrence ranks.
__device__ void dedup_block(const int* e2src, int c2, int* s_e, int* s_scan,
                            int* s_uniq, int* s_slot, int* s_kv) {
  int t = threadIdx.x;
  if (t < c2) s_e[t] = e2src[t];
  __syncthreads();
  int s = 0, firstIdx = t;
  if (t < c2) {
    s = s_e[t];
    for (int q = 0; q < t; ++q) if (s_e[q] == s) { firstIdx = q; break; }
  }
  s_scan[t] = (t < c2 && firstIdx == t) ? 1 : 0;
  __syncthreads();
  for (int off = 1; off < 256; off <<= 1) {       // inclusive Hillis-Steele
    int add = (t >= off) ? s_scan[t - off] : 0;
    __syncthreads();
    s_scan[t] += add;
    __syncthreads();
  }
  if (t < c2 && firstIdx == t) s_uniq[s_scan[t] - 1] = s;
  __syncthreads();
  if (t < c2) s_slot[t] = s_scan[firstIdx] - 1;
  if (t == 0) {
    int K1 = (c2 > 0) ? s_scan[255] : 0;
    int kd = -1;
    for (int i = 0; i < K1; ++i) if (s_uniq[i] == TGT) { kd = i; break; }
    if (kd < 0) { s_uniq[K1] = TGT; kd = K1; K1++; }
    s_kv[0] = K1; s_kv[1] = kd;
  }
  __syncthreads();
}

// ---- K1: transpose W1/W2; scan edges with dst == TGT ----
__global__ __launch_bounds__(256) void k_scan2(const int* __restrict__ eidx,
    const float* __restrict__ W1, const float* __restrict__ W2, char* ws) {
  WS w = carve(ws);
  int tid = blockIdx.x * 256 + threadIdx.x;
  int nthreads = gridDim.x * 256;
  for (int i = tid; i < 65536; i += nthreads) {
    int o = i >> 8, c = i & 255;
    w.W1T[c * 256 + o] = W1[i];
    w.W2T[c * 256 + o] = W2[i];
  }
  const int* esrc = eidx;
  const int4* edst4 = (const int4*)(eidx + N_EDGES);
  for (int i = tid; i < N_EDGES / 4; i += nthreads) {
    int4 d = edst4[i];
    int dv[4] = {d.x, d.y, d.z, d.w};
#pragma unroll
    for (int j = 0; j < 4; ++j)
      if (dv[j] == TGT) {
        int p = atomicAdd(&w.cnt[0], 1);
        if (p < C2MAX) w.e2src[p] = esrc[4 * i + j];
      }
  }
}

// ---- K2: per-block dedup; scan edges into dst set -> per-dst lists ----
__global__ __launch_bounds__(256) void k_scan1(const int* __restrict__ eidx, char* ws) {
  WS w = carve(ws);
  __shared__ int s_e[C2MAX], s_scan[256], s_uniq[KCAP], s_slot[C2MAX], s_kv[2];
  int c2 = min(w.cnt[0], C2MAX);
  dedup_block(w.e2src, c2, s_e, s_scan, s_uniq, s_slot, s_kv);
  int K1 = s_kv[0];
  if (blockIdx.x == 0) {
    int t = threadIdx.x;
    if (t < K1) w.g_uniq[t] = s_uniq[t];
    if (t < c2) w.g_slot[t] = s_slot[t];
    if (t == 0) { w.g_misc[0] = K1; w.g_misc[1] = s_kv[1]; }
  }
  int tid = blockIdx.x * 256 + threadIdx.x;
  int nthreads = gridDim.x * 256;
  const int* esrc = eidx;
  const int4* edst4 = (const int4*)(eidx + N_EDGES);
  for (int i = tid; i < N_EDGES / 4; i += nthreads) {
    int4 d = edst4[i];
    int dv[4] = {d.x, d.y, d.z, d.w};
#pragma unroll
    for (int j = 0; j < 4; ++j) {
      int k = -1;
      for (int q = 0; q < K1; ++q) if (s_uniq[q] == dv[j]) { k = q; break; }
      if (k >= 0) {
        int p = atomicAdd(&w.cnt2[k], 1);
        if (p < ELMAX) w.l1src[k * ELMAX + p] = esrc[4 * i + j];
      }
    }
  }
}

// ---- K3: one block per (dst, 4-item batch): xw1 + att dots ----
// Item j < ne is edge source j; item j == ne is the dst node itself.
__global__ __launch_bounds__(256) void k_xw1(const float* __restrict__ x,
    const float* __restrict__ aS1, const float* __restrict__ aD1, char* ws) {
  WS w = carve(ws);
  int k = blockIdx.x;
  if (k >= w.g_misc[0]) return;
  int t = threadIdx.x;
  int ne = min(w.cnt2[k], ELMAX);
  int items = ne + 1;
  __shared__ __align__(16) float s_xsT[4 * 256];
  __shared__ float s_redS[4 * 256], s_redD[4 * 256];
  int myNode = w.g_uniq[k];

  for (int b = blockIdx.y; b * 4 < items; b += PBLK) {
    int base = b * 4;
    int na = min(4, items - base);
    for (int i = 0; i < na; ++i) {
      int it = base + i;
      int node = (it < ne) ? w.l1src[k * ELMAX + it] : myNode;
      s_xsT[t * 4 + i] = x[(size_t)node * 256 + t];
    }
    __syncthreads();
    float a0 = 0.f, a1 = 0.f, a2 = 0.f, a3 = 0.f;
#pragma unroll 16
    for (int c = 0; c < 256; ++c) {
      float wv = w.W1T[c * 256 + t];                 // lane-coalesced, L2/L3-resident
      float4 xv = *(const float4*)&s_xsT[c * 4];     // LDS broadcast
      a0 = fmaf(xv.x, wv, a0); a1 = fmaf(xv.y, wv, a1);
      a2 = fmaf(xv.z, wv, a2); a3 = fmaf(xv.w, wv, a3);
    }
    float accs[4] = {a0, a1, a2, a3};
    for (int i = 0; i < na; ++i) {
      int row = k * ROWS + base + i;
      w.g_xw1[(size_t)row * 256 + t] = accs[i];
      s_redS[i * 256 + t] = accs[i] * aS1[t];
      s_redD[i * 256 + t] = accs[i] * aD1[t];
    }
    __syncthreads();
    if (t < 32) {
      int i = t >> 3, h = t & 7;
      if (i < na) {
        float s = 0.f, dd = 0.f;
        for (int q = 0; q < 32; ++q) {
          s  += s_redS[i * 256 + h * 32 + q];
          dd += s_redD[i * 256 + h * 32 + q];
        }
        int row = k * ROWS + base + i;
        w.g_as1[row * 8 + h] = s;
        w.g_ad1[row * 8 + h] = dd;
      }
    }
    __syncthreads();
  }
}

// ---- K4: one block per dst: softmax + aggregate + GELU + xw2 ----
__global__ __launch_bounds__(256) void k_attn(const float* __restrict__ b1,
    const float* __restrict__ aS2, const float* __restrict__ aD2, char* ws) {
  WS w = carve(ws);
  int k = blockIdx.x;
  if (k >= w.g_misc[0]) return;
  int t = threadIdx.x;
  int ne = min(w.cnt2[k], ELMAX);
  __shared__ float s_as[ROWS * 8];
  __shared__ float s_p[ELMAX * 8];
  __shared__ float s_den[8];
  __shared__ float s_h1[256];
  __shared__ float s_redS[256], s_redD[256];
  for (int i = t; i < (ne + 1) * 8; i += 256) s_as[i] = w.g_as1[(k * ROWS) * 8 + i];
  __syncthreads();
  if (t < 8) {                                       // per-head softmax weights
    int h = t;
    float adst = w.g_ad1[(k * ROWS + ne) * 8 + h];
    float m = -INFINITY;
    for (int j = 0; j < ne; ++j) {
      float e = s_as[j * 8 + h] + adst;
      e = (e >= 0.f) ? e : 0.2f * e;
      m = fmaxf(m, e);
    }
    float den = 0.f;
    for (int j = 0; j < ne; ++j) {
      float e = s_as[j * 8 + h] + adst;
      e = (e >= 0.f) ? e : 0.2f * e;
      float p = expf(e - m);
      s_p[j * 8 + h] = p;
      den += p;
    }
    s_den[h] = den + 1e-16f;
  }
  __syncthreads();
  int h = t >> 5;
  float acc = 0.f;
  const float* xwb = w.g_xw1 + (size_t)(k * ROWS) * 256 + t;
#pragma unroll 4
  for (int j = 0; j < ne; ++j)
    acc = fmaf(s_p[j * 8 + h], xwb[(size_t)j * 256], acc);
  float o = (ne > 0) ? acc / s_den[h] : 0.f;
  o += b1[t];
  s_h1[t] = 0.5f * o * (1.f + erff(o * 0.70710678118654752440f));  // exact GELU
  __syncthreads();
  float a2s = 0.f;
#pragma unroll 16
  for (int c = 0; c < 256; ++c)
    a2s = fmaf(s_h1[c], w.W2T[c * 256 + t], a2s);
  w.g_xw2[k * 256 + t] = a2s;
  s_redS[t] = a2s * aS2[t];
  s_redD[t] = a2s * aD2[t];
  __syncthreads();
  if (t < 8) {
    float s = 0.f, dd = 0.f;
    for (int q = 0; q < 32; ++q) { s += s_redS[t * 32 + q]; dd += s_redD[t * 32 + q]; }
    w.g_as2[k * 8 + t] = s;
    w.g_ad2[k * 8 + t] = dd;
  }
}

// ---- K5: layer-2 attention for node TGT ----
__global__ __launch_bounds__(256) void k_final(const float* __restrict__ b2,
                                               float* __restrict__ out, char* ws) {
  WS w = carve(ws);
  int t = threadIdx.x;
  int c2 = min(w.cnt[0], C2MAX);
  int kd = w.g_misc[1];
  __shared__ int s_slot[C2MAX];
  __shared__ float s_p[C2MAX];
  __shared__ float s_den[8];
  if (t < c2) s_slot[t] = w.g_slot[t];
  __syncthreads();
  int h = t >> 5;
  if (t < 8) {
    float adst = w.g_ad2[kd * 8 + t];
    float m = -INFINITY;
    for (int j = 0; j < c2; ++j) {
      float e = w.g_as2[s_slot[j] * 8 + t] + adst;
      e = (e >= 0.f) ? e : 0.2f * e;
      m = fmaxf(m, e);
    }
    float den = 0.f;
    for (int j = 0; j < c2; ++j) {
      float e = w.g_as2[s_slot[j] * 8 + t] + adst;
      e = (e >= 0.f) ? e : 0.2f * e;
      den += expf(e - m);
    }
    s_den[t] = den + 1e-16f;
    // stash m reusing s_p tail region is avoided; recompute per-head below
  }
  __syncthreads();
  // per-head exp weights for all heads sequentially would duplicate work; instead
  // each of 8 leader threads fills its head's weights:
  if (t < 8) {
    float adst = w.g_ad2[kd * 8 + t];
    float m = -INFINITY;
    for (int j = 0; j < c2; ++j) {
      float e = w.g_as2[s_slot[j] * 8 + t] + adst;
      e = (e >= 0.f) ? e : 0.2f * e;
      m = fmaxf(m, e);
    }
    for (int j = 0; j < c2; ++j) {
      float e = w.g_as2[s_slot[j] * 8 + t] + adst;
      e = (e >= 0.f) ? e : 0.2f * e;
      // pack per-head weights interleaved: s_p[j] only valid per head via stride trick
    }
  }
  __syncthreads();
  float adst = w.g_ad2[kd * 8 + h];
  float m = -INFINITY;
  for (int j = 0; j < c2; ++j) {
    float e = w.g_as2[s_slot[j] * 8 + h] + adst;
    e = (e >= 0.f) ? e : 0.2f * e;
    m = fmaxf(m, e);
  }
  float acc = 0.f;
  for (int j = 0; j < c2; ++j) {
    int kk = s_slot[j];
    float e = w.g_as2[kk * 8 + h] + adst;
    e = (e >= 0.f) ? e : 0.2f * e;
    float p = expf(e - m);
    acc = fmaf(p, w.g_xw2[kk * 256 + t], acc);
  }
  float o = (c2 > 0) ? acc / s_den[h] : 0.f;
  out[t] = o + b2[t];
}

extern "C" void kernel_launch(void* const* d_in, const int* in_sizes, int n_in,
                              void* d_out, int out_size, void* d_ws, size_t ws_size,
                              hipStream_t stream) {
  const float* x    = (const float*)d_in[0];
  const int*   eidx = (const int*)d_in[1];
  const float* W1   = (const float*)d_in[2];
  const float* aS1  = (const float*)d_in[3];
  const float* aD1  = (const float*)d_in[4];
  const float* b1   = (const float*)d_in[5];
  const float* W2   = (const float*)d_in[6];
  const float* aS2  = (const float*)d_in[7];
  const float* aD2  = (const float*)d_in[8];
  const float* b2   = (const float*)d_in[9];
  float* out = (float*)d_out;
  char*  ws  = (char*)d_ws;

  hipMemsetAsync(ws, 0, (16 + 272) * sizeof(int), stream);  // cnt + cnt2

  k_scan2<<<SCANBLK, 256, 0, stream>>>(eidx, W1, W2, ws);
  k_scan1<<<SCANBLK, 256, 0, stream>>>(eidx, ws);
  k_xw1  <<<dim3(KCAP, PBLK), 256, 0, stream>>>(x, aS1, aD1, ws);
  k_attn <<<KCAP, 256, 0, stream>>>(b1, aS2, aD2, ws);
  k_final<<<1, 256, 0, stream>>>(b2, out, ws);
}